// Round 6
// baseline (106.536 us; speedup 1.0000x reference)
//
#include <hip/hip_runtime.h>

#define LOG2E 1.4426950408889634f

typedef __attribute__((ext_vector_type(8))) short short8;
typedef __attribute__((ext_vector_type(4))) float f32x4;

__device__ __forceinline__ unsigned short f2bf(float f) {
  unsigned int u = __float_as_uint(f);
  u = (u + 0x7fffu + ((u >> 16) & 1u)) >> 16;   // RNE, finite inputs only
  return (unsigned short)u;
}

// ---------------------------------------------------------------------------
// Kernel 1: f = X @ W^T + b  (fp32 SGEMM, 128x128 tile, 8x8/thread)
// Emits: ft (bf16, layout [b][n/16][h][c][n%16]) and s_src/s_dst ([b][h][n],
// f32, PRE-SCALED by log2(e) so k2 can use raw v_exp_f32).
// ---------------------------------------------------------------------------
__global__ __launch_bounds__(256) void gat_k1(
    const float* __restrict__ X, const float* __restrict__ W,
    const float* __restrict__ bias, const float* __restrict__ a,
    unsigned short* __restrict__ ft, float* __restrict__ ssrc,
    float* __restrict__ sdst)
{
  __shared__ float Xs[8][128];
  __shared__ float Ws[8][128];
  const int tid = threadIdx.x;
  const int tx = tid & 15, ty = tid >> 4;
  const int m0 = blockIdx.x * 128;
  const int c0 = blockIdx.y * 128;

  float acc[8][8];
#pragma unroll
  for (int r = 0; r < 8; ++r)
#pragma unroll
    for (int j = 0; j < 8; ++j) acc[r][j] = 0.f;

  const int lrow = tid >> 1;
  const int kk0 = (tid & 1) * 4;
  const float* Xp = X + (size_t)(m0 + lrow) * 256 + kk0;
  const float* Wp = W + (size_t)(c0 + lrow) * 256 + kk0;

  for (int kc = 0; kc < 256; kc += 8) {
    float4 xv = *(const float4*)(Xp + kc);
    float4 wv = *(const float4*)(Wp + kc);
    __syncthreads();
    Xs[kk0 + 0][lrow] = xv.x; Xs[kk0 + 1][lrow] = xv.y;
    Xs[kk0 + 2][lrow] = xv.z; Xs[kk0 + 3][lrow] = xv.w;
    Ws[kk0 + 0][lrow] = wv.x; Ws[kk0 + 1][lrow] = wv.y;
    Ws[kk0 + 2][lrow] = wv.z; Ws[kk0 + 3][lrow] = wv.w;
    __syncthreads();
#pragma unroll
    for (int kk = 0; kk < 8; ++kk) {
      float av[8], wv8[8];
#pragma unroll
      for (int r = 0; r < 8; ++r) av[r] = Xs[kk][ty * 8 + r];
#pragma unroll
      for (int j = 0; j < 8; ++j) wv8[j] = Ws[kk][tx * 8 + j];
#pragma unroll
      for (int r = 0; r < 8; ++r)
#pragma unroll
        for (int j = 0; j < 8; ++j) acc[r][j] = fmaf(av[r], wv8[j], acc[r][j]);
    }
  }

  const int b = m0 >> 11;
  const int nloc0 = (m0 & 2047) + ty * 8;
  const int cg0 = c0 + tx * 8;
  const int h = cg0 >> 6;
  const int cb = cg0 & 63;

  float bv[8], av_s[8], av_d[8];
#pragma unroll
  for (int j = 0; j < 8; ++j) {
    bv[j]   = bias[cg0 + j];
    av_s[j] = a[h * 128 + cb + j];
    av_d[j] = a[h * 128 + 64 + cb + j];
  }
#pragma unroll
  for (int r = 0; r < 8; ++r)
#pragma unroll
    for (int j = 0; j < 8; ++j) acc[r][j] += bv[j];

  const int jt = nloc0 >> 4;
  const int ni = nloc0 & 15;
#pragma unroll
  for (int j = 0; j < 8; ++j) {
    unsigned int u[4];
#pragma unroll
    for (int q = 0; q < 4; ++q) {
      unsigned int lo = f2bf(acc[2 * q + 0][j]);
      unsigned int hi = f2bf(acc[2 * q + 1][j]);
      u[q] = lo | (hi << 16);
    }
    size_t off = ((((size_t)b * 128 + jt) * 4 + h) * 64 + (cb + j)) * 16 + ni;
    *(uint4*)(ft + off) = make_uint4(u[0], u[1], u[2], u[3]);
  }

  float sp[8], dp[8];
#pragma unroll
  for (int r = 0; r < 8; ++r) {
    float s = 0.f, d = 0.f;
#pragma unroll
    for (int j = 0; j < 8; ++j) {
      s = fmaf(acc[r][j], av_s[j], s);
      d = fmaf(acc[r][j], av_d[j], d);
    }
    sp[r] = s; dp[r] = d;
  }
#pragma unroll
  for (int off = 1; off < 8; off <<= 1) {
#pragma unroll
    for (int r = 0; r < 8; ++r) {
      sp[r] += __shfl_xor(sp[r], off);
      dp[r] += __shfl_xor(dp[r], off);
    }
  }
  if ((tx & 7) == 0) {
    float* sb = ssrc + ((size_t)b * 4 + h) * 2048 + nloc0;
    float* db = sdst + ((size_t)b * 4 + h) * 2048 + nloc0;
#pragma unroll
    for (int r = 0; r < 8; ++r) { sb[r] = sp[r] * LOG2E; db[r] = dp[r] * LOG2E; }
  }
}

// ---------------------------------------------------------------------------
// Kernel 2: fused mask + leaky-relu + softmax + PV (bf16 MFMA 16x16x32)
// Grid 1024 blocks (b = idx&7 XCD-pinned, itile = idx>>3, 16 i-rows) =
// 4 blocks/CU = 32 waves/CU. 512 thr = 8 waves = (head h, j-half p).
// Wave: 32 steps of 32 j's; per step 8 exps + 4 MFMAs (c-blocks 0..3).
// Fragment roles: A[m=i=lane&15][k=j, kgroup=lane>>4], B[k=j][n=c=lane&15].
// PROLOGUE: stream 16 adj rows (128 KB, once grid-wide) -> bit words in LDS;
// stage s_dst (32 KB). Zero barriers in main loop; TLP (8 waves/SIMD) hides
// ft L2/L3 latency.
// ---------------------------------------------------------------------------
__global__ __launch_bounds__(512, 8) void gat_k2(
    const int* __restrict__ adj, const unsigned short* __restrict__ ft,
    const float* __restrict__ ssrc, const float* __restrict__ sdst,
    float* __restrict__ out)
{
  __shared__ __align__(16) unsigned char lds[37120];  // sd 32KB | Aw [64][17] u32
  float* sd = (float*)lds;                            // [4][2048] f32
  unsigned* Aw = (unsigned*)(lds + 32768);            // [64][17] u32

  const int tid = threadIdx.x;
  const int b = blockIdx.x & 7;
  const int itile = blockIdx.x >> 3;     // 0..127
  const int i0 = itile * 16;
  const int w = tid >> 6;
  const int h = w >> 1;                  // head
  const int p = w & 1;                   // j-half
  const int lane = tid & 63;
  const int i_l = lane & 15;             // i row within tile / c within c-block
  const int kg = lane >> 4;              // k-group 0..3
  const int shamt = kg * 8;

  // ---- stage s_dst (32 KB contiguous) ----
  {
    const float4* src = (const float4*)(sdst + (size_t)b * 4 * 2048);
    float4* dst = (float4*)sd;
#pragma unroll
    for (int q = 0; q < 4; ++q) dst[tid + q * 512] = src[tid + q * 512];
  }
  // ---- stream adj rows i0..i0+15 (128 KB), pack -> Aw[word][row] ----
  {
    const int* abase = adj + (size_t)b * 2048 * 2048 + (size_t)i0 * 2048;
    unsigned short* dst16 = (unsigned short*)Aw;
#pragma unroll
    for (int k = 0; k < 4; ++k) {
      const int idx = k * 512 + tid;          // [0,2048)
      const int r = idx >> 7;                 // row 0..15
      const int s16 = idx & 127;              // 16-col group
      const int4* ap = (const int4*)(abase + (size_t)r * 2048 + s16 * 16);
      int4 v0 = ap[0], v1 = ap[1], v2 = ap[2], v3 = ap[3];
      int vv[16] = {v0.x, v0.y, v0.z, v0.w, v1.x, v1.y, v1.z, v1.w,
                    v2.x, v2.y, v2.z, v2.w, v3.x, v3.y, v3.z, v3.w};
      unsigned m = 0;
#pragma unroll
      for (int i = 0; i < 16; ++i) m |= (vv[i] ? 1u : 0u) << i;
      dst16[((s16 >> 1) * 17 + r) * 2 + (s16 & 1)] = (unsigned short)m;
    }
  }
  const float si = ssrc[((size_t)b * 4 + h) * 2048 + i0 + i_l];
  const float* sdh = sd + h * 2048 + p * 1024 + kg * 8;
  // ft element base for this thread (jt0 = p*64 + (kg>>1), c = c0 + i_l, ni0 = (kg&1)*8)
  const unsigned short* ftb =
      ft + ((((size_t)b * 128 + p * 64 + (kg >> 1)) * 4 + h) * 64 + i_l) * 16 +
      (kg & 1) * 8;

  f32x4 acc0, acc1, acc2, acc3;
#pragma unroll
  for (int q = 0; q < 4; ++q) { acc0[q] = 0.f; acc1[q] = 0.f; acc2[q] = 0.f; acc3[q] = 0.f; }
  float lsum = 0.f;

  __syncthreads();

#define COMP(s)                                                   \
  {                                                               \
    const unsigned wrd = Aw[(p * 32 + (s)) * 17 + i_l];           \
    const unsigned byte_ = (wrd >> shamt) & 0xffu;                \
    const float* tp_ = sdh + (s) * 32;                            \
    float4 t0_ = *(const float4*)tp_;                             \
    float4 t1_ = *(const float4*)(tp_ + 4);                       \
    float tj_[8] = {t0_.x, t0_.y, t0_.z, t0_.w,                   \
                    t1_.x, t1_.y, t1_.z, t1_.w};                  \
    float e_[8];                                                  \
    _Pragma("unroll")                                             \
    for (int q = 0; q < 8; ++q) {                                 \
      float x_ = si + tj_[q];                                     \
      float y_ = fmaxf(x_, 0.2f * x_);                            \
      float ev_ = __builtin_amdgcn_exp2f(y_);                     \
      ev_ = (byte_ & (1u << q)) ? ev_ : 0.f;                      \
      e_[q] = ev_;                                                \
      lsum += ev_;                                                \
    }                                                             \
    union { unsigned u[4]; short8 v; } af_;                       \
    _Pragma("unroll")                                             \
    for (int q2 = 0; q2 < 4; ++q2) {                              \
      unsigned r_;                                                \
      asm("v_cvt_pk_bf16_f32 %0, %1, %2"                          \
          : "=v"(r_) : "v"(e_[2 * q2]), "v"(e_[2 * q2 + 1]));     \
      af_.u[q2] = r_;                                             \
    }                                                             \
    const unsigned short* fp_ = ftb + (size_t)(s) * 8192;         \
    union { uint4 q; short8 v; } b0_, b1_, b2_, b3_;              \
    b0_.q = *(const uint4*)(fp_);                                 \
    b1_.q = *(const uint4*)(fp_ + 256);                           \
    b2_.q = *(const uint4*)(fp_ + 512);                           \
    b3_.q = *(const uint4*)(fp_ + 768);                           \
    acc0 = __builtin_amdgcn_mfma_f32_16x16x32_bf16(af_.v, b0_.v, acc0, 0, 0, 0); \
    acc1 = __builtin_amdgcn_mfma_f32_16x16x32_bf16(af_.v, b1_.v, acc1, 0, 0, 0); \
    acc2 = __builtin_amdgcn_mfma_f32_16x16x32_bf16(af_.v, b2_.v, acc2, 0, 0, 0); \
    acc3 = __builtin_amdgcn_mfma_f32_16x16x32_bf16(af_.v, b3_.v, acc3, 0, 0, 0); \
  }

#pragma unroll 4
  for (int s = 0; s < 32; ++s) {
    COMP(s)
  }
#undef COMP

  // ---- epilogue: fold k-groups, combine p=0/p=1, normalize, store ----
  float lsum2 = lsum + __shfl_xor(lsum, 16);
  lsum2 += __shfl_xor(lsum2, 32);               // per-i, this p-half's sum
  float* ep = (float*)lds;                      // [4][16][64] f32 = 16 KB
  float* el = (float*)(lds + 16384);            // [4][16] f32
  __syncthreads();                              // done reading sd/Aw
  if (p == 1) {
#pragma unroll
    for (int r = 0; r < 4; ++r) {
      const int row = kg * 4 + r;
      ep[(h * 16 + row) * 64 + 0  + i_l] = acc0[r];
      ep[(h * 16 + row) * 64 + 16 + i_l] = acc1[r];
      ep[(h * 16 + row) * 64 + 32 + i_l] = acc2[r];
      ep[(h * 16 + row) * 64 + 48 + i_l] = acc3[r];
    }
    if (lane < 16) el[h * 16 + lane] = lsum2;
  }
  __syncthreads();
  if (p == 0) {
    const float L = lsum2 + el[h * 16 + i_l];
    const float rinv = 1.0f / L;
    float* ob = out + ((size_t)(b * 2048 + i0)) * 256 + h * 64;
#pragma unroll
    for (int r = 0; r < 4; ++r) {
      const int row = kg * 4 + r;
      const float ri = __shfl(rinv, row);
      ob[(size_t)row * 256 + 0  + i_l] = (acc0[r] + ep[(h * 16 + row) * 64 + 0  + i_l]) * ri;
      ob[(size_t)row * 256 + 16 + i_l] = (acc1[r] + ep[(h * 16 + row) * 64 + 16 + i_l]) * ri;
      ob[(size_t)row * 256 + 32 + i_l] = (acc2[r] + ep[(h * 16 + row) * 64 + 32 + i_l]) * ri;
      ob[(size_t)row * 256 + 48 + i_l] = (acc3[r] + ep[(h * 16 + row) * 64 + 48 + i_l]) * ri;
    }
  }
}

// ---------------------------------------------------------------------------
extern "C" void kernel_launch(void* const* d_in, const int* in_sizes, int n_in,
                              void* d_out, int out_size, void* d_ws, size_t ws_size,
                              hipStream_t stream) {
  const float* X    = (const float*)d_in[0];   // (8,2048,256) f32
  const int*   adj  = (const int*)d_in[1];     // (8,2048,2048) i32
  const float* W    = (const float*)d_in[2];   // (256,256) f32
  const float* bias = (const float*)d_in[3];   // (256,) f32
  const float* a    = (const float*)d_in[4];   // (4,128) f32
  float* out = (float*)d_out;

  unsigned short* ft = (unsigned short*)d_ws;                    // 8 MB bf16
  float* ssrc = (float*)((char*)d_ws + 8388608);                 // 256 KB
  float* sdst = ssrc + 8 * 4 * 2048;                             // 256 KB

  gat_k1<<<dim3(128, 2, 1), 256, 0, stream>>>(X, W, bias, a, ft, ssrc, sdst);
  gat_k2<<<dim3(1024, 1, 1), 512, 0, stream>>>(adj, ft, ssrc, sdst, out);
}